// Round 1
// baseline (206.975 us; speedup 1.0000x reference)
//
#include <hip/hip_runtime.h>

// B=8, S=256, T=32, D=512, He=512, Fd=128
// flat row r = b*S+s for E/L1/F arrays ([2048,512]); r = b*T+t for O/O2/O3 ([256,512])

typedef __attribute__((ext_vector_type(8))) short bf16x8;
typedef __attribute__((ext_vector_type(4))) float f32x4;

__device__ __forceinline__ unsigned short f2bf(float x) {
    union { float f; unsigned u; } v; v.f = x;
    unsigned r = v.u + 0x7fffu + ((v.u >> 16) & 1u);
    return (unsigned short)(r >> 16);
}

// ---- fp32 -> bf16 elementwise for E (1024 blk), Z (256 blk), O (128 blk) ----
__global__ __launch_bounds__(256) void cvt_all_k(
    const float* __restrict__ E, const float* __restrict__ Z, const float* __restrict__ O,
    unsigned short* __restrict__ Ebf, unsigned short* __restrict__ Zbf, unsigned short* __restrict__ Obf)
{
    int b = blockIdx.x;
    const float* src; unsigned short* dst; int base;
    if (b < 1024)      { src = E; dst = Ebf; base = b; }
    else if (b < 1280) { src = Z; dst = Zbf; base = b - 1024; }
    else               { src = O; dst = Obf; base = b - 1280; }
    int i = base * 1024 + threadIdx.x * 4;
    float4 v = *(const float4*)(src + i);
    ushort4 r;
    r.x = f2bf(v.x); r.y = f2bf(v.y); r.z = f2bf(v.z); r.w = f2bf(v.w);
    *(ushort4*)(dst + i) = r;
}

// ---- W [K,512] fp32 -> WT [512,K] bf16 (z: 0=W1,1=W2,2=W3(K=128),3=W4) ----
__global__ __launch_bounds__(256) void transpose_all_k(
    const float* __restrict__ W1, const float* __restrict__ W2,
    const float* __restrict__ W3, const float* __restrict__ W4,
    unsigned short* __restrict__ W1T, unsigned short* __restrict__ W2T,
    unsigned short* __restrict__ W3T, unsigned short* __restrict__ W4T)
{
    const float* W; unsigned short* WT; int K;
    switch (blockIdx.z) {
      case 0:  W = W1; WT = W1T; K = 512; break;
      case 1:  W = W2; WT = W2T; K = 512; break;
      case 2:  W = W3; WT = W3T; K = 128; break;
      default: W = W4; WT = W4T; K = 512; break;
    }
    int k0 = blockIdx.y * 32;
    if (k0 >= K) return;
    int n0 = blockIdx.x * 32;
    __shared__ float tile[32][33];
    int tx = threadIdx.x, ty = threadIdx.y; // (32,8)
    #pragma unroll
    for (int i = 0; i < 32; i += 8)
        tile[ty + i][tx] = W[(k0 + ty + i) * 512 + n0 + tx];
    __syncthreads();
    #pragma unroll
    for (int i = 0; i < 32; i += 8)
        WT[(n0 + ty + i) * K + k0 + tx] = f2bf(tile[tx][ty + i]);
}

// ---- merged MFMA GEMM: C = tanh(A @ BT^T + bias), N=512 fixed ----
// z=0: L1=tanh(E@W1) M=2048 K=512 | z=1: F=tanh(Z@W3) M=2048 K=128
// z=2: O2=tanh(O@W2) M=256 K=512  | z=3: O3=tanh(O@W4) M=256 K=512
__global__ __launch_bounds__(256) void gemm_all_k(
    const unsigned short* __restrict__ Ebf, const unsigned short* __restrict__ Zbf,
    const unsigned short* __restrict__ Obf,
    const unsigned short* __restrict__ W1T, const unsigned short* __restrict__ W3T,
    const unsigned short* __restrict__ W2T, const unsigned short* __restrict__ W4T,
    const float* __restrict__ b1, const float* __restrict__ b3,
    const float* __restrict__ b2, const float* __restrict__ b4,
    float* __restrict__ L1, float* __restrict__ F,
    float* __restrict__ O2, float* __restrict__ O3)
{
    const unsigned short* A; const unsigned short* BT; const float* bias; float* C;
    int M, K;
    switch (blockIdx.z) {
      case 0:  A = Ebf; BT = W1T; bias = b1; C = L1; M = 2048; K = 512; break;
      case 1:  A = Zbf; BT = W3T; bias = b3; C = F;  M = 2048; K = 128; break;
      case 2:  A = Obf; BT = W2T; bias = b2; C = O2; M = 256;  K = 512; break;
      default: A = Obf; BT = W4T; bias = b4; C = O3; M = 256;  K = 512; break;
    }
    int m0 = blockIdx.x * 64;
    if (m0 >= M) return;
    int n0 = blockIdx.y * 64;

    // stride 40 shorts (80B): 16B-aligned for b128 and conflict-light (2-way max)
    __shared__ unsigned short As[64 * 40];
    __shared__ unsigned short Bs[64 * 40];

    int tid  = threadIdx.x;
    int wave = tid >> 6;
    int lane = tid & 63;
    int lm   = lane & 15;   // m (A) / n (B) / col (C)
    int lq   = lane >> 4;   // k-quad

    int srow = tid >> 2;        // 0..63
    int scol = (tid & 3) * 8;   // 0,8,16,24

    f32x4 acc[4];
    #pragma unroll
    for (int c = 0; c < 4; ++c) acc[c] = f32x4{0.f, 0.f, 0.f, 0.f};

    for (int k0 = 0; k0 < K; k0 += 32) {
        __syncthreads();
        *(uint4*)(&As[srow * 40 + scol]) = *(const uint4*)(&A[(m0 + srow) * K + k0 + scol]);
        *(uint4*)(&Bs[srow * 40 + scol]) = *(const uint4*)(&BT[(n0 + srow) * K + k0 + scol]);
        __syncthreads();
        // A-frag: A[m=lm][k=lq*8+j]; B-frag: BT[n=lm][k=lq*8+j]
        bf16x8 af = *(const bf16x8*)(&As[(wave * 16 + lm) * 40 + lq * 8]);
        #pragma unroll
        for (int c = 0; c < 4; ++c) {
            bf16x8 bfr = *(const bf16x8*)(&Bs[(c * 16 + lm) * 40 + lq * 8]);
            acc[c] = __builtin_amdgcn_mfma_f32_16x16x32_bf16(af, bfr, acc[c], 0, 0, 0);
        }
    }

    // C/D layout: col = lane&15, row = (lane>>4)*4 + r
    #pragma unroll
    for (int c = 0; c < 4; ++c) {
        int col = n0 + c * 16 + lm;
        float bv = bias[col];
        #pragma unroll
        for (int r = 0; r < 4; ++r) {
            int row = m0 + wave * 16 + lq * 4 + r;
            float x = acc[c][r] + bv;
            x = fminf(fmaxf(x, -15.f), 15.f);
            float t = __expf(2.0f * x);           // tanh(x) = (e^2x - 1)/(e^2x + 1)
            C[row * 512 + col] = (t - 1.0f) / (t + 1.0f);
        }
    }
}

// ---- fused dual attention ----
// gamma[b,s,t,d] = softmax_s( L1[b,s,d]*O2[b,t,d] + F[b,s,d]*O3[b,t,d] )
// contex[b,t,d] = sum_s gamma * Enc[b,s,d];  attn[b,t,s,d] = gamma
__global__ __launch_bounds__(256) void attn_k(
    const float* __restrict__ L1, const float* __restrict__ F,
    const float* __restrict__ O2, const float* __restrict__ O3,
    const float* __restrict__ Enc, const float* __restrict__ Out,
    float* __restrict__ out0, float* __restrict__ attn)
{
    int bt = blockIdx.x;                       // b*32 + t
    int d  = blockIdx.y * 256 + threadIdx.x;   // 0..511
    int b  = bt >> 5;

    float c2 = O2[bt * 512 + d];
    float c3 = O3[bt * 512 + d];
    const float* L1b = L1  + (b * 256) * 512 + d;
    const float* Fb  = F   + (b * 256) * 512 + d;
    const float* Eb  = Enc + (b * 256) * 512 + d;

    float sum = 0.f, csum = 0.f;
    #pragma unroll 8
    for (int s = 0; s < 256; ++s) {
        float z = L1b[s * 512] * c2 + Fb[s * 512] * c3;
        float e = __expf(z);
        sum  += e;
        csum += e * Eb[s * 512];
    }
    float inv = 1.0f / sum;

    // concat_vectors: [Out | contex]
    out0[bt * 1024 + d]       = Out[bt * 512 + d];
    out0[bt * 1024 + 512 + d] = csum * inv;

    float* ap = attn + (bt * 256) * 512 + d;
    #pragma unroll 8
    for (int s = 0; s < 256; ++s) {
        float z = L1b[s * 512] * c2 + Fb[s * 512] * c3;
        ap[s * 512] = __expf(z) * inv;
    }
}

extern "C" void kernel_launch(void* const* d_in, const int* in_sizes, int n_in,
                              void* d_out, int out_size, void* d_ws, size_t ws_size,
                              hipStream_t stream)
{
    const float* Out = (const float*)d_in[0];   // [8,32,512]
    const float* Enc = (const float*)d_in[1];   // [256,8,512] -> flat [2048,512]
    const float* Z   = (const float*)d_in[2];   // [8,256,128] -> flat [2048,128]
    const float* W1  = (const float*)d_in[3];
    const float* b1  = (const float*)d_in[4];
    const float* W2  = (const float*)d_in[5];
    const float* b2  = (const float*)d_in[6];
    const float* W3  = (const float*)d_in[7];
    const float* b3  = (const float*)d_in[8];
    const float* W4  = (const float*)d_in[9];
    const float* b4  = (const float*)d_in[10];

    char* ws = (char*)d_ws;
    size_t off = 0;
    auto alloc = [&](size_t n) -> char* {
        char* p = ws + off; off += (n + 255) & ~(size_t)255; return p;
    };
    unsigned short* Ebf = (unsigned short*)alloc(1048576 * 2);
    unsigned short* Zbf = (unsigned short*)alloc(262144 * 2);
    unsigned short* Obf = (unsigned short*)alloc(131072 * 2);
    unsigned short* W1T = (unsigned short*)alloc(262144 * 2);
    unsigned short* W2T = (unsigned short*)alloc(262144 * 2);
    unsigned short* W3T = (unsigned short*)alloc(65536 * 2);
    unsigned short* W4T = (unsigned short*)alloc(262144 * 2);
    float* L1 = (float*)alloc(1048576 * 4);
    float* F  = (float*)alloc(1048576 * 4);
    float* O2 = (float*)alloc(131072 * 4);
    float* O3 = (float*)alloc(131072 * 4);

    float* out0 = (float*)d_out;            // [8,32,1024] = 262144
    float* attn = out0 + 262144;            // [8,32,256,512]

    hipLaunchKernelGGL(cvt_all_k, dim3(1408), dim3(256), 0, stream,
                       Enc, Z, Out, Ebf, Zbf, Obf);
    hipLaunchKernelGGL(transpose_all_k, dim3(16, 16, 4), dim3(32, 8), 0, stream,
                       W1, W2, W3, W4, W1T, W2T, W3T, W4T);
    hipLaunchKernelGGL(gemm_all_k, dim3(32, 8, 4), dim3(256), 0, stream,
                       Ebf, Zbf, Obf, W1T, W3T, W2T, W4T,
                       b1, b3, b2, b4, L1, F, O2, O3);
    hipLaunchKernelGGL(attn_k, dim3(256, 2), dim3(256), 0, stream,
                       L1, F, O2, O3, Enc, Out, out0, attn);
}

// Round 2
// 206.550 us; speedup vs baseline: 1.0021x; 1.0021x over previous
//
#include <hip/hip_runtime.h>

// B=8, S=256, T=32, D=512, He=512, Fd=128
// flat row r = b*S+s for E/L1/F ([2048,512]); r = b*T+t for O/O2/O3 ([256,512])

typedef __attribute__((ext_vector_type(8))) short bf16x8;
typedef __attribute__((ext_vector_type(4))) float f32x4;

__device__ __forceinline__ unsigned short f2bf(float x) {
    union { float f; unsigned u; } v; v.f = x;
    unsigned r = v.u + 0x7fffu + ((v.u >> 16) & 1u);
    return (unsigned short)(r >> 16);
}

// ---- fp32 -> bf16 elementwise for E (1024 blk), Z (256 blk), O (128 blk) ----
__global__ __launch_bounds__(256) void cvt_all_k(
    const float* __restrict__ E, const float* __restrict__ Z, const float* __restrict__ O,
    unsigned short* __restrict__ Ebf, unsigned short* __restrict__ Zbf, unsigned short* __restrict__ Obf)
{
    int b = blockIdx.x;
    const float* src; unsigned short* dst; int base;
    if (b < 1024)      { src = E; dst = Ebf; base = b; }
    else if (b < 1280) { src = Z; dst = Zbf; base = b - 1024; }
    else               { src = O; dst = Obf; base = b - 1280; }
    int i = base * 1024 + threadIdx.x * 4;
    float4 v = *(const float4*)(src + i);
    ushort4 r;
    r.x = f2bf(v.x); r.y = f2bf(v.y); r.z = f2bf(v.z); r.w = f2bf(v.w);
    *(ushort4*)(dst + i) = r;
}

// ---- W [K,512] fp32 -> WT [512,K] bf16 (z: 0=W1,1=W2,2=W3(K=128),3=W4) ----
__global__ __launch_bounds__(256) void transpose_all_k(
    const float* __restrict__ W1, const float* __restrict__ W2,
    const float* __restrict__ W3, const float* __restrict__ W4,
    unsigned short* __restrict__ W1T, unsigned short* __restrict__ W2T,
    unsigned short* __restrict__ W3T, unsigned short* __restrict__ W4T)
{
    const float* W; unsigned short* WT; int K;
    switch (blockIdx.z) {
      case 0:  W = W1; WT = W1T; K = 512; break;
      case 1:  W = W2; WT = W2T; K = 512; break;
      case 2:  W = W3; WT = W3T; K = 128; break;
      default: W = W4; WT = W4T; K = 512; break;
    }
    int k0 = blockIdx.y * 32;
    if (k0 >= K) return;
    int n0 = blockIdx.x * 32;
    __shared__ float tile[32][33];
    int tx = threadIdx.x, ty = threadIdx.y; // (32,8)
    #pragma unroll
    for (int i = 0; i < 32; i += 8)
        tile[ty + i][tx] = W[(k0 + ty + i) * 512 + n0 + tx];
    __syncthreads();
    #pragma unroll
    for (int i = 0; i < 32; i += 8)
        WT[(n0 + ty + i) * K + k0 + tx] = f2bf(tile[tx][ty + i]);
}

// ---- merged MFMA GEMM: C = tanh(A @ BT^T + bias), N=512 fixed ----
__global__ __launch_bounds__(256) void gemm_all_k(
    const unsigned short* __restrict__ Ebf, const unsigned short* __restrict__ Zbf,
    const unsigned short* __restrict__ Obf,
    const unsigned short* __restrict__ W1T, const unsigned short* __restrict__ W3T,
    const unsigned short* __restrict__ W2T, const unsigned short* __restrict__ W4T,
    const float* __restrict__ b1, const float* __restrict__ b3,
    const float* __restrict__ b2, const float* __restrict__ b4,
    float* __restrict__ L1, float* __restrict__ F,
    float* __restrict__ O2, float* __restrict__ O3)
{
    const unsigned short* A; const unsigned short* BT; const float* bias; float* C;
    int M, K;
    switch (blockIdx.z) {
      case 0:  A = Ebf; BT = W1T; bias = b1; C = L1; M = 2048; K = 512; break;
      case 1:  A = Zbf; BT = W3T; bias = b3; C = F;  M = 2048; K = 128; break;
      case 2:  A = Obf; BT = W2T; bias = b2; C = O2; M = 256;  K = 512; break;
      default: A = Obf; BT = W4T; bias = b4; C = O3; M = 256;  K = 512; break;
    }
    int m0 = blockIdx.x * 64;
    if (m0 >= M) return;
    int n0 = blockIdx.y * 64;

    __shared__ unsigned short As[64 * 40];
    __shared__ unsigned short Bs[64 * 40];

    int tid  = threadIdx.x;
    int wave = tid >> 6;
    int lane = tid & 63;
    int lm   = lane & 15;
    int lq   = lane >> 4;

    int srow = tid >> 2;
    int scol = (tid & 3) * 8;

    f32x4 acc[4];
    #pragma unroll
    for (int c = 0; c < 4; ++c) acc[c] = f32x4{0.f, 0.f, 0.f, 0.f};

    for (int k0 = 0; k0 < K; k0 += 32) {
        __syncthreads();
        *(uint4*)(&As[srow * 40 + scol]) = *(const uint4*)(&A[(m0 + srow) * K + k0 + scol]);
        *(uint4*)(&Bs[srow * 40 + scol]) = *(const uint4*)(&BT[(n0 + srow) * K + k0 + scol]);
        __syncthreads();
        bf16x8 af = *(const bf16x8*)(&As[(wave * 16 + lm) * 40 + lq * 8]);
        #pragma unroll
        for (int c = 0; c < 4; ++c) {
            bf16x8 bfr = *(const bf16x8*)(&Bs[(c * 16 + lm) * 40 + lq * 8]);
            acc[c] = __builtin_amdgcn_mfma_f32_16x16x32_bf16(af, bfr, acc[c], 0, 0, 0);
        }
    }

    #pragma unroll
    for (int c = 0; c < 4; ++c) {
        int col = n0 + c * 16 + lm;
        float bv = bias[col];
        #pragma unroll
        for (int r = 0; r < 4; ++r) {
            int row = m0 + wave * 16 + lq * 4 + r;
            float x = acc[c][r] + bv;
            x = fminf(fmaxf(x, -15.f), 15.f);
            float t = __expf(2.0f * x);
            C[row * 512 + col] = (t - 1.0f) / (t + 1.0f);
        }
    }
}

// ---- attention stage A: partial sums over s-chunks, with t-reuse ----
// block: (b, sc in 8 chunks of 32 s, tc in 2 halves of 16 t, dc in 2 halves of 256 d)
// sum_p/csum_p layout: [((b*8+sc)*32 + t)*512 + d]
__global__ __launch_bounds__(256) void attn_partial_k(
    const float* __restrict__ L1, const float* __restrict__ F,
    const float* __restrict__ O2, const float* __restrict__ O3,
    const float* __restrict__ Enc,
    float* __restrict__ sum_p, float* __restrict__ csum_p)
{
    int b  = blockIdx.x >> 3;
    int sc = blockIdx.x & 7;
    int tc = blockIdx.y;
    int dc = blockIdx.z;
    int d  = dc * 256 + threadIdx.x;

    float c2[16], c3[16], sum[16], csum[16];
    #pragma unroll
    for (int i = 0; i < 16; ++i) {
        int bt = b * 32 + tc * 16 + i;
        c2[i] = O2[bt * 512 + d];
        c3[i] = O3[bt * 512 + d];
        sum[i] = 0.f; csum[i] = 0.f;
    }

    int s0 = sc * 32;
    const float* L1b = L1  + (b * 256 + s0) * 512 + d;
    const float* Fb  = F   + (b * 256 + s0) * 512 + d;
    const float* Eb  = Enc + (b * 256 + s0) * 512 + d;

    #pragma unroll 2
    for (int s = 0; s < 32; ++s) {
        float l1 = L1b[s * 512];
        float f  = Fb[s * 512];
        float eh = Eb[s * 512];
        #pragma unroll
        for (int i = 0; i < 16; ++i) {
            float e = __expf(l1 * c2[i] + f * c3[i]);
            sum[i]  += e;
            csum[i] += e * eh;
        }
    }

    #pragma unroll
    for (int i = 0; i < 16; ++i) {
        int idx = ((b * 8 + sc) * 32 + tc * 16 + i) * 512 + d;
        sum_p[idx]  = sum[i];
        csum_p[idx] = csum[i];
    }
}

// ---- attention stage B: reduce partials -> inv, contex, copy Out ----
__global__ __launch_bounds__(256) void attn_finalize_k(
    const float* __restrict__ sum_p, const float* __restrict__ csum_p,
    const float* __restrict__ Out,
    float* __restrict__ out0, float* __restrict__ invA)
{
    int bt = blockIdx.x;          // b*32+t
    int d  = blockIdx.y * 256 + threadIdx.x;
    int b  = bt >> 5, t = bt & 31;

    float sum = 0.f, csum = 0.f;
    #pragma unroll
    for (int sc = 0; sc < 8; ++sc) {
        int idx = ((b * 8 + sc) * 32 + t) * 512 + d;
        sum  += sum_p[idx];
        csum += csum_p[idx];
    }
    float inv = 1.0f / sum;
    invA[bt * 512 + d] = inv;
    out0[bt * 1024 + d]       = Out[bt * 512 + d];
    out0[bt * 1024 + 512 + d] = csum * inv;
}

// ---- attention stage C: recompute exp, write gamma (132 MB stream) ----
// block: (b, sc in 64 chunks of 4 s); thread: 2 s x 4 d (float4)
__global__ __launch_bounds__(256) void attn_write_k(
    const float* __restrict__ L1, const float* __restrict__ F,
    const float* __restrict__ O2, const float* __restrict__ O3,
    const float* __restrict__ invA,
    float* __restrict__ attn)
{
    int b  = blockIdx.x;
    int s0 = blockIdx.y * 4 + ((threadIdx.x >> 7) * 2);   // this thread's first s
    int d4 = (threadIdx.x & 127) * 4;

    float4 l1[2], f[2];
    #pragma unroll
    for (int j = 0; j < 2; ++j) {
        l1[j] = *(const float4*)(L1 + (b * 256 + s0 + j) * 512 + d4);
        f[j]  = *(const float4*)(F  + (b * 256 + s0 + j) * 512 + d4);
    }

    for (int t = 0; t < 32; ++t) {
        int bt = b * 32 + t;
        float4 c2 = *(const float4*)(O2   + bt * 512 + d4);
        float4 c3 = *(const float4*)(O3   + bt * 512 + d4);
        float4 iv = *(const float4*)(invA + bt * 512 + d4);
        #pragma unroll
        for (int j = 0; j < 2; ++j) {
            float4 g;
            g.x = __expf(l1[j].x * c2.x + f[j].x * c3.x) * iv.x;
            g.y = __expf(l1[j].y * c2.y + f[j].y * c3.y) * iv.y;
            g.z = __expf(l1[j].z * c2.z + f[j].z * c3.z) * iv.z;
            g.w = __expf(l1[j].w * c2.w + f[j].w * c3.w) * iv.w;
            *(float4*)(attn + ((size_t)(bt * 256 + s0 + j)) * 512 + d4) = g;
        }
    }
}

extern "C" void kernel_launch(void* const* d_in, const int* in_sizes, int n_in,
                              void* d_out, int out_size, void* d_ws, size_t ws_size,
                              hipStream_t stream)
{
    const float* Out = (const float*)d_in[0];
    const float* Enc = (const float*)d_in[1];
    const float* Z   = (const float*)d_in[2];
    const float* W1  = (const float*)d_in[3];
    const float* b1  = (const float*)d_in[4];
    const float* W2  = (const float*)d_in[5];
    const float* b2  = (const float*)d_in[6];
    const float* W3  = (const float*)d_in[7];
    const float* b3  = (const float*)d_in[8];
    const float* W4  = (const float*)d_in[9];
    const float* b4  = (const float*)d_in[10];

    char* ws = (char*)d_ws;
    size_t off = 0;
    auto alloc = [&](size_t n) -> char* {
        char* p = ws + off; off += (n + 255) & ~(size_t)255; return p;
    };
    unsigned short* Ebf = (unsigned short*)alloc(1048576 * 2);
    unsigned short* Zbf = (unsigned short*)alloc(262144 * 2);
    unsigned short* Obf = (unsigned short*)alloc(131072 * 2);
    unsigned short* W1T = (unsigned short*)alloc(262144 * 2);
    unsigned short* W2T = (unsigned short*)alloc(262144 * 2);
    unsigned short* W3T = (unsigned short*)alloc(65536 * 2);
    unsigned short* W4T = (unsigned short*)alloc(262144 * 2);
    float* L1    = (float*)alloc(1048576 * 4);
    float* F     = (float*)alloc(1048576 * 4);
    float* O2    = (float*)alloc(131072 * 4);
    float* O3    = (float*)alloc(131072 * 4);
    float* sum_p = (float*)alloc(1048576 * 4);
    float* csum_p= (float*)alloc(1048576 * 4);
    float* invA  = (float*)alloc(131072 * 4);

    float* out0 = (float*)d_out;            // [8,32,1024]
    float* attn = out0 + 262144;            // [8,32,256,512]

    hipLaunchKernelGGL(cvt_all_k, dim3(1408), dim3(256), 0, stream,
                       Enc, Z, Out, Ebf, Zbf, Obf);
    hipLaunchKernelGGL(transpose_all_k, dim3(16, 16, 4), dim3(32, 8), 0, stream,
                       W1, W2, W3, W4, W1T, W2T, W3T, W4T);
    hipLaunchKernelGGL(gemm_all_k, dim3(32, 8, 4), dim3(256), 0, stream,
                       Ebf, Zbf, Obf, W1T, W3T, W2T, W4T,
                       b1, b3, b2, b4, L1, F, O2, O3);
    hipLaunchKernelGGL(attn_partial_k, dim3(64, 2, 2), dim3(256), 0, stream,
                       L1, F, O2, O3, Enc, sum_p, csum_p);
    hipLaunchKernelGGL(attn_finalize_k, dim3(256, 2), dim3(256), 0, stream,
                       sum_p, csum_p, Out, out0, invA);
    hipLaunchKernelGGL(attn_write_k, dim3(8, 64), dim3(256), 0, stream,
                       L1, F, O2, O3, invA, attn);
}

// Round 3
// 202.630 us; speedup vs baseline: 1.0214x; 1.0193x over previous
//
#include <hip/hip_runtime.h>

// B=8, S=256, T=32, D=512, He=512, Fd=128
// flat row r = b*S+s for E/L1/F ([2048,512]); r = b*T+t for O/O2/O3 ([256,512])

typedef __attribute__((ext_vector_type(8))) short bf16x8;
typedef __attribute__((ext_vector_type(4))) float f32x4;

__device__ __forceinline__ unsigned short f2bf(float x) {
    union { float f; unsigned u; } v; v.f = x;
    unsigned r = v.u + 0x7fffu + ((v.u >> 16) & 1u);
    return (unsigned short)(r >> 16);
}

// ---- fused prep: blocks 0..1407 = fp32->bf16 cvt (E,Z,O); 1408..2239 = W transpose ----
__global__ __launch_bounds__(256) void prep_k(
    const float* __restrict__ E, const float* __restrict__ Z, const float* __restrict__ O,
    const float* __restrict__ W1, const float* __restrict__ W2,
    const float* __restrict__ W3, const float* __restrict__ W4,
    unsigned short* __restrict__ Ebf, unsigned short* __restrict__ Zbf,
    unsigned short* __restrict__ Obf,
    unsigned short* __restrict__ W1T, unsigned short* __restrict__ W2T,
    unsigned short* __restrict__ W3T, unsigned short* __restrict__ W4T)
{
    int bid = blockIdx.x;
    if (bid < 1408) {
        const float* src; unsigned short* dst; int base;
        if (bid < 1024)      { src = E; dst = Ebf; base = bid; }
        else if (bid < 1280) { src = Z; dst = Zbf; base = bid - 1024; }
        else                 { src = O; dst = Obf; base = bid - 1280; }
        int i = base * 1024 + threadIdx.x * 4;
        float4 v = *(const float4*)(src + i);
        ushort4 r;
        r.x = f2bf(v.x); r.y = f2bf(v.y); r.z = f2bf(v.z); r.w = f2bf(v.w);
        *(ushort4*)(dst + i) = r;
        return;
    }
    int tb = bid - 1408;
    const float* W; unsigned short* WT; int K;
    if (tb < 256)      {            W = W1; WT = W1T; K = 512; }
    else if (tb < 512) { tb -= 256; W = W2; WT = W2T; K = 512; }
    else if (tb < 576) { tb -= 512; W = W3; WT = W3T; K = 128; }
    else               { tb -= 576; W = W4; WT = W4T; K = 512; }
    int n0 = (tb & 15) * 32;
    int k0 = (tb >> 4) * 32;
    __shared__ float tile[32][33];
    int tx = threadIdx.x & 31, ty = threadIdx.x >> 5;  // 32 x 8
    #pragma unroll
    for (int i = 0; i < 32; i += 8)
        tile[ty + i][tx] = W[(k0 + ty + i) * 512 + n0 + tx];
    __syncthreads();
    #pragma unroll
    for (int i = 0; i < 32; i += 8)
        WT[(n0 + ty + i) * K + k0 + tx] = f2bf(tile[tx][ty + i]);
}

// ---- merged MFMA GEMM: C = tanh(A @ BT^T + bias), N=512, BK=64, packed 1D grid ----
// ids 0..255: L1 (M=2048,K=512) | 256..511: F (M=2048,K=128)
// 512..543: O2 (M=256,K=512)    | 544..575: O3 (M=256,K=512)
__global__ __launch_bounds__(256) void gemm_all_k(
    const unsigned short* __restrict__ Ebf, const unsigned short* __restrict__ Zbf,
    const unsigned short* __restrict__ Obf,
    const unsigned short* __restrict__ W1T, const unsigned short* __restrict__ W3T,
    const unsigned short* __restrict__ W2T, const unsigned short* __restrict__ W4T,
    const float* __restrict__ b1, const float* __restrict__ b3,
    const float* __restrict__ b2, const float* __restrict__ b4,
    float* __restrict__ L1, float* __restrict__ F,
    float* __restrict__ O2, float* __restrict__ O3)
{
    int id = blockIdx.x;
    const unsigned short* A; const unsigned short* BT; const float* bias; float* C;
    int K;
    if (id < 256)      {             A = Ebf; BT = W1T; bias = b1; C = L1; K = 512; }
    else if (id < 512) { id -= 256;  A = Zbf; BT = W3T; bias = b3; C = F;  K = 128; }
    else if (id < 544) { id -= 512;  A = Obf; BT = W2T; bias = b2; C = O2; K = 512; }
    else               { id -= 544;  A = Obf; BT = W4T; bias = b4; C = O3; K = 512; }
    int m0 = (id >> 3) * 64;
    int n0 = (id & 7) * 64;

    // stride 72 shorts (144B): 16B-aligned for b128, 2-way conflicts max (free)
    __shared__ unsigned short As[64 * 72];
    __shared__ unsigned short Bs[64 * 72];

    int tid  = threadIdx.x;
    int wave = tid >> 6;
    int lane = tid & 63;
    int lm   = lane & 15;
    int lq   = lane >> 4;

    int srow = tid >> 2;          // 0..63
    int scol = (tid & 3) * 16;    // 0,16,32,48 (shorts)

    f32x4 acc[4];
    #pragma unroll
    for (int c = 0; c < 4; ++c) acc[c] = f32x4{0.f, 0.f, 0.f, 0.f};

    for (int k0 = 0; k0 < K; k0 += 64) {
        __syncthreads();
        const unsigned short* Ap = &A[(m0 + srow) * K + k0 + scol];
        const unsigned short* Bp = &BT[(n0 + srow) * K + k0 + scol];
        *(uint4*)(&As[srow * 72 + scol])     = *(const uint4*)(Ap);
        *(uint4*)(&As[srow * 72 + scol + 8]) = *(const uint4*)(Ap + 8);
        *(uint4*)(&Bs[srow * 72 + scol])     = *(const uint4*)(Bp);
        *(uint4*)(&Bs[srow * 72 + scol + 8]) = *(const uint4*)(Bp + 8);
        __syncthreads();
        #pragma unroll
        for (int ks = 0; ks < 2; ++ks) {
            bf16x8 af = *(const bf16x8*)(&As[(wave * 16 + lm) * 72 + ks * 32 + lq * 8]);
            #pragma unroll
            for (int c = 0; c < 4; ++c) {
                bf16x8 bfr = *(const bf16x8*)(&Bs[(c * 16 + lm) * 72 + ks * 32 + lq * 8]);
                acc[c] = __builtin_amdgcn_mfma_f32_16x16x32_bf16(af, bfr, acc[c], 0, 0, 0);
            }
        }
    }

    // C/D layout: col = lane&15, row = (lane>>4)*4 + r  (verified round 1)
    #pragma unroll
    for (int c = 0; c < 4; ++c) {
        int col = n0 + c * 16 + lm;
        float bv = bias[col];
        #pragma unroll
        for (int r = 0; r < 4; ++r) {
            int row = m0 + wave * 16 + lq * 4 + r;
            float x = acc[c][r] + bv;
            x = fminf(fmaxf(x, -15.f), 15.f);
            float t = __expf(2.0f * x);
            C[row * 512 + col] = (t - 1.0f) / (t + 1.0f);
        }
    }
}

// ---- attention stage A: partials over 16-s chunks, 8 t per block, 1024 blocks ----
// partial layout: [((b*16+sc)*32 + t)*512 + d]
__global__ __launch_bounds__(256) void attn_partial_k(
    const float* __restrict__ L1, const float* __restrict__ F,
    const float* __restrict__ O2, const float* __restrict__ O3,
    const float* __restrict__ Enc,
    float* __restrict__ sum_p, float* __restrict__ csum_p)
{
    int b  = blockIdx.x >> 4;
    int sc = blockIdx.x & 15;
    int tc = blockIdx.y;                  // 0..3 -> 8 t each
    int d  = blockIdx.z * 256 + threadIdx.x;

    float c2[8], c3[8], sum[8], csum[8];
    #pragma unroll
    for (int i = 0; i < 8; ++i) {
        int bt = b * 32 + tc * 8 + i;
        c2[i] = O2[bt * 512 + d];
        c3[i] = O3[bt * 512 + d];
        sum[i] = 0.f; csum[i] = 0.f;
    }

    int s0 = sc * 16;
    const float* L1b = L1  + (b * 256 + s0) * 512 + d;
    const float* Fb  = F   + (b * 256 + s0) * 512 + d;
    const float* Eb  = Enc + (b * 256 + s0) * 512 + d;

    #pragma unroll 2
    for (int s = 0; s < 16; ++s) {
        float l1 = L1b[s * 512];
        float f  = Fb[s * 512];
        float eh = Eb[s * 512];
        #pragma unroll
        for (int i = 0; i < 8; ++i) {
            float e = __expf(l1 * c2[i] + f * c3[i]);
            sum[i]  += e;
            csum[i] += e * eh;
        }
    }

    #pragma unroll
    for (int i = 0; i < 8; ++i) {
        int idx = ((b * 16 + sc) * 32 + tc * 8 + i) * 512 + d;
        sum_p[idx]  = sum[i];
        csum_p[idx] = csum[i];
    }
}

// ---- attention stage B: reduce 16 partials -> inv, contex, copy Out ----
__global__ __launch_bounds__(256) void attn_finalize_k(
    const float* __restrict__ sum_p, const float* __restrict__ csum_p,
    const float* __restrict__ Out,
    float* __restrict__ out0, float* __restrict__ invA)
{
    int bt = blockIdx.x;
    int d  = blockIdx.y * 256 + threadIdx.x;
    int b  = bt >> 5, t = bt & 31;

    float sum = 0.f, csum = 0.f;
    #pragma unroll
    for (int sc = 0; sc < 16; ++sc) {
        int idx = ((b * 16 + sc) * 32 + t) * 512 + d;
        sum  += sum_p[idx];
        csum += csum_p[idx];
    }
    float inv = 1.0f / sum;
    invA[bt * 512 + d] = inv;
    out0[bt * 1024 + d]       = Out[bt * 512 + d];
    out0[bt * 1024 + 512 + d] = csum * inv;
}

// ---- attention stage C: recompute exp, nontemporal 134 MB gamma stream ----
// grid (8 b, 32 s-chunks of 8); thread: 4 s x 4 d; b pinned to XCD (idx%8==b)
__global__ __launch_bounds__(256) void attn_write_k(
    const float* __restrict__ L1, const float* __restrict__ F,
    const float* __restrict__ O2, const float* __restrict__ O3,
    const float* __restrict__ invA,
    float* __restrict__ attn)
{
    int b     = blockIdx.x;
    int sbase = blockIdx.y * 8 + (threadIdx.x >> 7) * 4;
    int d4    = (threadIdx.x & 127) * 4;

    f32x4 l1[4], f[4];
    #pragma unroll
    for (int j = 0; j < 4; ++j) {
        l1[j] = *(const f32x4*)(L1 + (b * 256 + sbase + j) * 512 + d4);
        f[j]  = *(const f32x4*)(F  + (b * 256 + sbase + j) * 512 + d4);
    }

    for (int t = 0; t < 32; ++t) {
        int bt = b * 32 + t;
        f32x4 c2 = *(const f32x4*)(O2   + bt * 512 + d4);
        f32x4 c3 = *(const f32x4*)(O3   + bt * 512 + d4);
        f32x4 iv = *(const f32x4*)(invA + bt * 512 + d4);
        #pragma unroll
        for (int j = 0; j < 4; ++j) {
            f32x4 g;
            g[0] = __expf(l1[j][0] * c2[0] + f[j][0] * c3[0]) * iv[0];
            g[1] = __expf(l1[j][1] * c2[1] + f[j][1] * c3[1]) * iv[1];
            g[2] = __expf(l1[j][2] * c2[2] + f[j][2] * c3[2]) * iv[2];
            g[3] = __expf(l1[j][3] * c2[3] + f[j][3] * c3[3]) * iv[3];
            __builtin_nontemporal_store(
                g, (f32x4*)(attn + ((size_t)(bt * 256 + sbase + j)) * 512 + d4));
        }
    }
}

extern "C" void kernel_launch(void* const* d_in, const int* in_sizes, int n_in,
                              void* d_out, int out_size, void* d_ws, size_t ws_size,
                              hipStream_t stream)
{
    const float* Out = (const float*)d_in[0];
    const float* Enc = (const float*)d_in[1];
    const float* Z   = (const float*)d_in[2];
    const float* W1  = (const float*)d_in[3];
    const float* b1  = (const float*)d_in[4];
    const float* W2  = (const float*)d_in[5];
    const float* b2  = (const float*)d_in[6];
    const float* W3  = (const float*)d_in[7];
    const float* b3  = (const float*)d_in[8];
    const float* W4  = (const float*)d_in[9];
    const float* b4  = (const float*)d_in[10];

    char* ws = (char*)d_ws;
    size_t off = 0;
    auto alloc = [&](size_t n) -> char* {
        char* p = ws + off; off += (n + 255) & ~(size_t)255; return p;
    };
    unsigned short* Ebf = (unsigned short*)alloc(1048576 * 2);
    unsigned short* Zbf = (unsigned short*)alloc(262144 * 2);
    unsigned short* Obf = (unsigned short*)alloc(131072 * 2);
    unsigned short* W1T = (unsigned short*)alloc(262144 * 2);
    unsigned short* W2T = (unsigned short*)alloc(262144 * 2);
    unsigned short* W3T = (unsigned short*)alloc(65536 * 2);
    unsigned short* W4T = (unsigned short*)alloc(262144 * 2);
    float* L1    = (float*)alloc(1048576 * 4);
    float* F     = (float*)alloc(1048576 * 4);
    float* O2    = (float*)alloc(131072 * 4);
    float* O3    = (float*)alloc(131072 * 4);
    float* sum_p = (float*)alloc(2097152 * 4);
    float* csum_p= (float*)alloc(2097152 * 4);
    float* invA  = (float*)alloc(131072 * 4);

    float* out0 = (float*)d_out;            // [8,32,1024]
    float* attn = out0 + 262144;            // [8,32,256,512]

    hipLaunchKernelGGL(prep_k, dim3(2240), dim3(256), 0, stream,
                       Enc, Z, Out, W1, W2, W3, W4,
                       Ebf, Zbf, Obf, W1T, W2T, W3T, W4T);
    hipLaunchKernelGGL(gemm_all_k, dim3(576), dim3(256), 0, stream,
                       Ebf, Zbf, Obf, W1T, W3T, W2T, W4T,
                       b1, b3, b2, b4, L1, F, O2, O3);
    hipLaunchKernelGGL(attn_partial_k, dim3(128, 4, 2), dim3(256), 0, stream,
                       L1, F, O2, O3, Enc, sum_p, csum_p);
    hipLaunchKernelGGL(attn_finalize_k, dim3(256, 2), dim3(256), 0, stream,
                       sum_p, csum_p, Out, out0, invA);
    hipLaunchKernelGGL(attn_write_k, dim3(8, 32), dim3(256), 0, stream,
                       L1, F, O2, O3, invA, attn);
}